// Round 10
// baseline (154.539 us; speedup 1.0000x reference)
//
#include <hip/hip_runtime.h>
#include <hip/hip_bf16.h>
#include <stdint.h>

#define D_MODEL 1024

typedef __attribute__((ext_vector_type(4))) float  f32x4;
typedef __attribute__((ext_vector_type(8))) __bf16 bf16x8;
typedef __attribute__((ext_vector_type(8))) unsigned short u16x8;
typedef __attribute__((ext_vector_type(4))) unsigned short u16x4;

// ---------- helpers ----------

__device__ __forceinline__ unsigned order_map(float x) {
    unsigned u = __float_as_uint(x);
    return (u & 0x80000000u) ? ~u : (u | 0x80000000u);
}
__device__ __forceinline__ float order_unmap(unsigned m) {
    unsigned b = (m & 0x80000000u) ? (m & 0x7fffffffu) : ~m;
    return __uint_as_float(b);
}
__device__ __forceinline__ unsigned short f2bf(float f) {
    unsigned u = __float_as_uint(f);
    u += 0x7fffu + ((u >> 16) & 1u);
    return (unsigned short)(u >> 16);
}

// ---------- prelude kernels (unchanged — at BW floor) ----------

__global__ void init_u32(unsigned* __restrict__ p, int n) {
    int i = blockIdx.x * blockDim.x + threadIdx.x;
    if (i < n) p[i] = 0u;
}

__global__ void colmax_kernel(const float* __restrict__ src, int rows_per_slab,
                              int cols, unsigned* __restrict__ out_u) {
    int k = blockIdx.x * blockDim.x + threadIdx.x;
    const float* p = src + (size_t)blockIdx.y * rows_per_slab * cols + k;
    float m = -__builtin_inff();
#pragma unroll 4
    for (int r = 0; r < rows_per_slab; ++r)
        m = fmaxf(m, p[(size_t)r * cols]);
    atomicMax(&out_u[k], order_map(m));
}

#define CC_ROWS 16
__global__ __launch_bounds__(256)
void colmax_convert(const float* __restrict__ x,
                    float* __restrict__ partial,
                    unsigned short* __restrict__ xb) {
    int c4 = threadIdx.x * 4;
    size_t base = (size_t)blockIdx.x * CC_ROWS * D_MODEL + c4;
    f32x4 m4 = {-__builtin_inff(), -__builtin_inff(), -__builtin_inff(), -__builtin_inff()};
#pragma unroll 8
    for (int r = 0; r < CC_ROWS; ++r) {
        f32x4 v = *reinterpret_cast<const f32x4*>(&x[base + (size_t)r * D_MODEL]);
        u16x4 o;
#pragma unroll
        for (int e = 0; e < 4; ++e) { m4[e] = fmaxf(m4[e], v[e]); o[e] = f2bf(v[e]); }
        *reinterpret_cast<u16x4*>(&xb[base + (size_t)r * D_MODEL]) = o;
    }
    *reinterpret_cast<f32x4*>(&partial[(size_t)blockIdx.x * D_MODEL + c4]) = m4;
}

__global__ void reduce_partial(const float* __restrict__ partial,
                               unsigned* __restrict__ ma_u) {
    int col  = blockIdx.x * 256 + threadIdx.x;
    int b0   = blockIdx.y * 64;
    float m = -__builtin_inff();
#pragma unroll 8
    for (int i = 0; i < 64; ++i)
        m = fmaxf(m, partial[(size_t)(b0 + i) * D_MODEL + col]);
    atomicMax(&ma_u[col], order_map(m));
}

__global__ void scale_kernel(const unsigned* __restrict__ ma_u,
                             const unsigned* __restrict__ mw_u,
                             float* __restrict__ s) {
    int k = blockIdx.x * blockDim.x + threadIdx.x;
    if (k < D_MODEL) {
        float ma = order_unmap(ma_u[k]);
        float mw = order_unmap(mw_u[k]);
        s[k] = sqrtf(ma) / sqrtf(mw);   // ALPHA = 0.5
    }
}

__global__ void build_w_kernel(const float* __restrict__ W, const float* __restrict__ s,
                               unsigned short* __restrict__ Wp) {
    int j  = blockIdx.x;
    int k4 = threadIdx.x * 4;
    float sj = s[j];
    f32x4 w  = *reinterpret_cast<const f32x4*>(&W[(size_t)j * D_MODEL + k4]);
    f32x4 sk = *reinterpret_cast<const f32x4*>(&s[k4]);
    u16x4 o;
#pragma unroll
    for (int i = 0; i < 4; ++i) o[i] = f2bf(sj * w[i] / sk[i]);
    *reinterpret_cast<u16x4*>(&Wp[(size_t)j * D_MODEL + k4]) = o;
}

// ---------- GEMM: 256x256, 8 waves (2Mx4N), BK=64, 8-phase fine interleave ----
// R10: faithful m201-style schedule. Chunks per K-tile (16 KB = 2 loads/thread):
//   A_q = rows {64q..64q+63} U {128+64q..} (the mq=q rows of both wr halves)
//   B_q = cols {32q + 64b + j} (the nq=q cols of all wc)           q in {0,1}
// Phase p of tile t: [ds_read quad frags][stage 1 chunk of t+1][vmcnt(4)]
//                    [barrier][setprio 16 MFMA setprio][barrier]
// Stage order A0,B0,B1,A1 == next tile's need order (ph0:A0+B0, ph1:B1, ph2:A1).
// vmcnt(4) leaves exactly the 2 newest chunks in flight; each need provably
// covered (see accounting in comments). Never drains to 0 mid-loop (T4).
#define GBM 256
#define GBN 256
#define GBK 64
#define GNT (D_MODEL / GBK)   // 16

__global__ __launch_bounds__(512)
void gemm_main(const unsigned short* __restrict__ Xb,
               const unsigned short* __restrict__ Wp,
               const float* __restrict__ bias,
               float* __restrict__ out) {
    __shared__ __align__(16) unsigned short As[2][GBM][GBK];   // 64 KB
    __shared__ __align__(16) unsigned short Bs[2][GBN][GBK];   // 64 KB

    int flat  = blockIdx.x;
    int xcd   = flat & 7;
    int j     = flat >> 3;                      // 0..63
    int col0  = (j & 3) * GBN;                  // 4 col panels
    int row0  = ((xcd << 4) + (j >> 2)) * GBM;  // within-XCD Xb reuse (R8, FETCH 49MB)

    int tid  = threadIdx.x;
    int wave = tid >> 6;
    int lane = tid & 63;
    int wr   = wave >> 2;      // 0..1 : rows wr*128
    int wc   = wave & 3;       // 0..3 : cols wc*64
    int l16  = lane & 15;
    int lq   = lane >> 4;      // 0..3 : k-quarter
    int srow  = lane >> 3;                   // staging row within 8-row group
    int skoff = ((lane & 7) ^ srow) << 3;    // pre-swizzled source k-offset (elems)

    f32x4 acc[2][2][4][2];
#pragma unroll
    for (int mq = 0; mq < 2; ++mq)
#pragma unroll
        for (int nq = 0; nq < 2; ++nq)
#pragma unroll
            for (int m = 0; m < 4; ++m)
#pragma unroll
                for (int n = 0; n < 2; ++n)
                    acc[mq][nq][m][n] = (f32x4){0.f, 0.f, 0.f, 0.f};

    // chunk stagers: 2 gload_lds per thread each (wave-uniform linear LDS dest,
    // pre-swizzled global source — rule #21)
    auto stageA_chunk = [&](int q, int t, int b) {
#pragma unroll
        for (int r = 0; r < 2; ++r) {
            int rb = q * 64 + r * 128 + wave * 8;    // multiple of 8
            const unsigned short* g =
                Xb + (size_t)(row0 + rb + srow) * D_MODEL + t * GBK + skoff;
            __builtin_amdgcn_global_load_lds(
                (const __attribute__((address_space(1))) void*)g,
                (__attribute__((address_space(3))) void*)&As[b][rb][0], 16, 0, 0);
        }
    };
    auto stageB_chunk = [&](int q, int t, int b) {
#pragma unroll
        for (int r = 0; r < 2; ++r) {
            int cb = q * 32 + (2 * r + (wave >> 2)) * 64 + (wave & 3) * 8;  // mult of 8
            const unsigned short* g =
                Wp + (size_t)(col0 + cb + srow) * D_MODEL + t * GBK + skoff;
            __builtin_amdgcn_global_load_lds(
                (const __attribute__((address_space(1))) void*)g,
                (__attribute__((address_space(3))) void*)&Bs[b][cb][0], 16, 0, 0);
        }
    };

    // prologue: full tile 0, hard wait (one-time)
    stageA_chunk(0, 0, 0); stageB_chunk(0, 0, 0);
    stageB_chunk(1, 0, 0); stageA_chunk(1, 0, 0);
    asm volatile("s_waitcnt vmcnt(0)" ::: "memory");
    __builtin_amdgcn_s_barrier();

    bf16x8 af[4][2], bf[2][2];

#pragma unroll 1
    for (int t = 0; t < GNT; ++t) {
        int cur = t & 1;
        int nb  = cur ^ 1;
        bool pf = (t + 1 < GNT);
        const char* Ab = (const char*)&As[cur][0][0];
        const char* Bb = (const char*)&Bs[cur][0][0];

        auto lda = [&](int mq, int m, int kk) {
            int row  = wr * 128 + mq * 64 + m * 16 + l16;
            int o    = ((lq << 4) + (kk << 6)) ^ ((row & 7) << 4);
            return *reinterpret_cast<const bf16x8*>(Ab + row * 128 + o);
        };
        auto ldb = [&](int nq, int n, int kk) {
            int row  = wc * 64 + nq * 32 + n * 16 + l16;
            int o    = ((lq << 4) + (kk << 6)) ^ ((row & 7) << 4);
            return *reinterpret_cast<const bf16x8*>(Bb + row * 128 + o);
        };
        auto quad = [&](int mq, int nq) {
            __builtin_amdgcn_s_setprio(1);
#pragma unroll
            for (int m = 0; m < 4; ++m)
#pragma unroll
                for (int n = 0; n < 2; ++n)
#pragma unroll
                    for (int kk = 0; kk < 2; ++kk)
                        acc[mq][nq][m][n] = __builtin_amdgcn_mfma_f32_16x16x32_bf16(
                            af[m][kk], bf[n][kk], acc[mq][nq][m][n], 0, 0, 0);
            __builtin_amdgcn_s_setprio(0);
        };

        // ---- ph0: quad(0,0). reads 8A+4B. stage A0(t+1).
        // vmcnt(4): A0(t+1),?.. only 2 outstanding -> instant; establishes pattern.
#pragma unroll
        for (int m = 0; m < 4; ++m)
#pragma unroll
            for (int kk = 0; kk < 2; ++kk) af[m][kk] = lda(0, m, kk);
#pragma unroll
        for (int n = 0; n < 2; ++n)
#pragma unroll
            for (int kk = 0; kk < 2; ++kk) bf[n][kk] = ldb(0, n, kk);
        if (pf) stageA_chunk(0, t + 1, nb);
        asm volatile("s_waitcnt vmcnt(4)" ::: "memory");   // covers B1(t) need @ph1
        __builtin_amdgcn_s_barrier();
        quad(0, 0);
        __builtin_amdgcn_s_barrier();

        // ---- ph1: quad(0,1). reads 4B (af reused). stage B0(t+1).
#pragma unroll
        for (int n = 0; n < 2; ++n)
#pragma unroll
            for (int kk = 0; kk < 2; ++kk) bf[n][kk] = ldb(1, n, kk);
        if (pf) stageB_chunk(0, t + 1, nb);
        asm volatile("s_waitcnt vmcnt(4)" ::: "memory");   // covers A1(t) need @ph2
        __builtin_amdgcn_s_barrier();
        quad(0, 1);
        __builtin_amdgcn_s_barrier();

        // ---- ph2: quad(1,1). reads 8A (bf nq1 reused). stage B1(t+1).
#pragma unroll
        for (int m = 0; m < 4; ++m)
#pragma unroll
            for (int kk = 0; kk < 2; ++kk) af[m][kk] = lda(1, m, kk);
        if (pf) stageB_chunk(1, t + 1, nb);
        asm volatile("s_waitcnt vmcnt(4)" ::: "memory");
        __builtin_amdgcn_s_barrier();
        quad(1, 1);
        __builtin_amdgcn_s_barrier();

        // ---- ph3: quad(1,0). reads 4B (af mq1 reused). stage A1(t+1).
        // vmcnt(4) here: outstanding A0,B0,B1,A1 of t+1 (8) -> waits A0,B0 landed
        // = exactly what t+1.ph0 reads. B1,A1 stay in flight (counted, not 0).
#pragma unroll
        for (int n = 0; n < 2; ++n)
#pragma unroll
            for (int kk = 0; kk < 2; ++kk) bf[n][kk] = ldb(0, n, kk);
        if (pf) stageA_chunk(1, t + 1, nb);
        asm volatile("s_waitcnt vmcnt(4)" ::: "memory");
        __builtin_amdgcn_s_barrier();
        quad(1, 0);
        __builtin_amdgcn_s_barrier();
    }

    // ---- epilogue: C/D col = lane&15, row = lq*4 + q ----
    int crow = row0 + wr * 128;
    int ccol = col0 + wc * 64;
#pragma unroll
    for (int nq = 0; nq < 2; ++nq)
#pragma unroll
        for (int n = 0; n < 2; ++n) {
            int col = ccol + nq * 32 + n * 16 + l16;
            float b = bias[col];
#pragma unroll
            for (int mq = 0; mq < 2; ++mq)
#pragma unroll
                for (int m = 0; m < 4; ++m) {
                    int r = crow + mq * 64 + m * 16 + lq * 4;
#pragma unroll
                    for (int q = 0; q < 4; ++q)
                        out[(size_t)(r + q) * D_MODEL + col] = acc[mq][nq][m][n][q] + b;
                }
        }
}

// fallback (ws too small for Xb): reg-staged f32->bf16, single buffer 128x128
__global__ __launch_bounds__(256)
void gemm_fallback(const float* __restrict__ X, const unsigned short* __restrict__ Wp,
                   const float* __restrict__ bias, float* __restrict__ out, int N) {
    __shared__ __align__(16) unsigned short As[128][64];
    __shared__ __align__(16) unsigned short Bs[128][64];

    int flat = blockIdx.x;
    int swz  = ((gridDim.x & 7) == 0)
             ? (flat & 7) * (gridDim.x >> 3) + (flat >> 3) : flat;
    const int nColBlk = D_MODEL / 128;
    int row0 = (swz / nColBlk) * 128;
    int col0 = (swz % nColBlk) * 128;

    int tid  = threadIdx.x;
    int wave = tid >> 6;
    int lane = tid & 63;
    int wr   = wave >> 1;
    int wc   = wave & 1;
    int l16  = lane & 15;
    int srow  = lane >> 3;
    int skoff = ((lane & 7) ^ srow) << 3;

    f32x4 acc[4][4];
#pragma unroll
    for (int m = 0; m < 4; ++m)
#pragma unroll
        for (int n = 0; n < 4; ++n)
            acc[m][n] = (f32x4){0.f, 0.f, 0.f, 0.f};

    for (int k0 = 0; k0 < D_MODEL; k0 += 64) {
        __syncthreads();
#pragma unroll
        for (int i = 0; i < 4; ++i) {
            int c   = i * 256 + tid;
            int r   = c >> 3;
            int seg = c & 7;
            const float* gp = X + (size_t)(row0 + r) * D_MODEL + k0 + seg * 8;
            f32x4 x0 = *reinterpret_cast<const f32x4*>(gp);
            f32x4 x1 = *reinterpret_cast<const f32x4*>(gp + 4);
            u16x8 v;
#pragma unroll
            for (int e = 0; e < 4; ++e) { v[e] = f2bf(x0[e]); v[e + 4] = f2bf(x1[e]); }
            int off = (seg * 16) ^ ((r & 7) << 4);
            *reinterpret_cast<u16x8*>((char*)&As[0][0] + r * 128 + off) = v;
        }
#pragma unroll
        for (int i = 0; i < 4; ++i) {
            int r0 = (wave * 4 + i) * 8;
            const unsigned short* g = Wp + (size_t)(col0 + r0 + srow) * D_MODEL + k0 + skoff;
            __builtin_amdgcn_global_load_lds(
                (const __attribute__((address_space(1))) void*)g,
                (__attribute__((address_space(3))) void*)&Bs[r0][0], 16, 0, 0);
        }
        __syncthreads();
#pragma unroll
        for (int kk = 0; kk < 2; ++kk) {
            bf16x8 af[4], bf_[4];
#pragma unroll
            for (int m = 0; m < 4; ++m) {
                int row = wr * 64 + m * 16 + l16;
                int o   = ((lane >> 4) * 16 + kk * 64) ^ ((row & 7) << 4);
                af[m] = *reinterpret_cast<const bf16x8*>((const char*)&As[0][0] + row * 128 + o);
            }
#pragma unroll
            for (int n = 0; n < 4; ++n) {
                int row = wc * 64 + n * 16 + l16;
                int o   = ((lane >> 4) * 16 + kk * 64) ^ ((row & 7) << 4);
                bf_[n] = *reinterpret_cast<const bf16x8*>((const char*)&Bs[0][0] + row * 128 + o);
            }
#pragma unroll
            for (int m = 0; m < 4; ++m)
#pragma unroll
                for (int n = 0; n < 4; ++n)
                    acc[m][n] = __builtin_amdgcn_mfma_f32_16x16x32_bf16(
                        af[m], bf_[n], acc[m][n], 0, 0, 0);
        }
    }

    int crow = row0 + wr * 64;
    int ccol = col0 + wc * 64;
#pragma unroll
    for (int n = 0; n < 4; ++n) {
        int col = ccol + n * 16 + l16;
        float b = bias[col];
#pragma unroll
        for (int m = 0; m < 4; ++m) {
            int r = crow + m * 16 + (lane >> 4) * 4;
#pragma unroll
            for (int q = 0; q < 4; ++q)
                out[(size_t)(r + q) * D_MODEL + col] = acc[m][n][q] + b;
        }
    }
}

// ---------- launch ----------

extern "C" void kernel_launch(void* const* d_in, const int* in_sizes, int n_in,
                              void* d_out, int out_size, void* d_ws, size_t ws_size,
                              hipStream_t stream) {
    const float* x    = (const float*)d_in[0];
    const float* w    = (const float*)d_in[1];
    const float* bias = (const float*)d_in[2];
    float* out        = (float*)d_out;
    const int N       = in_sizes[0] / D_MODEL;   // 32768

    char* ws               = (char*)d_ws;
    unsigned*       ma_u   = (unsigned*)(ws);
    unsigned*       mw_u   = (unsigned*)(ws + 4096);
    float*          s      = (float*)(ws + 8192);
    unsigned short* Wp     = (unsigned short*)(ws + 16384);
    unsigned short* Xb     = (unsigned short*)(ws + 16384 + (size_t)D_MODEL * D_MODEL * 2);
    const int nPart        = N / CC_ROWS;   // 2048
    float*          part   = (float*)(ws + 16384 + (size_t)D_MODEL * D_MODEL * 2
                                               + (size_t)N * D_MODEL * 2);

    size_t need = 16384 + (size_t)D_MODEL * D_MODEL * 2 + (size_t)N * D_MODEL * 2
                + (size_t)nPart * D_MODEL * 4;
    bool preconv = ws_size >= need;

    init_u32<<<8, 256, 0, stream>>>((unsigned*)ws, 2048);

    if (preconv) {
        colmax_convert<<<nPart, 256, 0, stream>>>(x, part, Xb);
        reduce_partial<<<dim3(D_MODEL / 256, nPart / 64), 256, 0, stream>>>(part, ma_u);
    } else {
        colmax_kernel<<<dim3(D_MODEL / 256, 64), 256, 0, stream>>>(x, N / 64, D_MODEL, ma_u);
    }
    colmax_kernel<<<dim3(D_MODEL / 256, 16), 256, 0, stream>>>(w, D_MODEL / 16, D_MODEL, mw_u);
    scale_kernel<<<D_MODEL / 256, 256, 0, stream>>>(ma_u, mw_u, s);
    build_w_kernel<<<D_MODEL, 256, 0, stream>>>(w, s, Wp);

    if (preconv) {
        int nblk = (N / GBM) * (D_MODEL / GBN);   // 512
        gemm_main<<<nblk, 512, 0, stream>>>(Xb, Wp, bias, out);
    } else {
        int nblk = (N / 128) * (D_MODEL / 128);
        gemm_fallback<<<nblk, 256, 0, stream>>>(x, Wp, bias, out, N);
    }
}